// Round 3
// baseline (174.556 us; speedup 1.0000x reference)
//
#include <hip/hip_runtime.h>
#include <math.h>

#define BPB 4
#define NBLK 1024
#define SCALE 0.17677669529663687f

typedef short short8 __attribute__((ext_vector_type(8)));
typedef float f32x4 __attribute__((ext_vector_type(4)));

__device__ __forceinline__ unsigned short f2bf(float x) {
  unsigned int u = __float_as_uint(x);
  u += 0x7fffu + ((u >> 16) & 1u);
  return (unsigned short)(u >> 16);
}
__device__ __forceinline__ unsigned pk2(float a, float b) {
  return (unsigned)f2bf(a) | ((unsigned)f2bf(b) << 16);
}
__device__ __forceinline__ float bf2f(unsigned int lo16) {
  return __uint_as_float(lo16 << 16);
}
// [16 rows][32 k] bf16 tile (1KB), XOR-swizzled 16B granules
__device__ __forceinline__ int tile_addr(int r, int k) {
  int g = k >> 3;
  int p = (g ^ ((r >> 1) & 3)) & 3;
  return r * 32 + p * 8 + (k & 7);
}
// row-major [rows][128] bf16, rotate-XOR swizzle
__device__ __forceinline__ int rm_addr(int r, int k) {
  int g = k >> 3;
  int r3 = r & 7;
  int rot = ((r3 << 2) | (r3 >> 1)) & 7;
  int p = (g & 8) | ((g & 7) ^ rot);
  return r * 128 + p * 8 + (k & 7);
}

// ---- single prep kernel ----
// wbf (shorts): fragment-major weights. W1 [0,16384): ((gi*16+f)*64+lane)*8
//   Wk [16384,49152): ((gi*32+f)*64+lane)*8 ; Wq [49152,81920): same
// wsf (floats at byte 163840): per gi stride 1024: vw2[4][128], vb2[4], const
__global__ void prep(const float* __restrict__ fc1_w, const float* __restrict__ qkv_w,
                     const float* __restrict__ qkv_b, const float* __restrict__ out_w,
                     const float* __restrict__ out_b, const float* __restrict__ fc2_w,
                     const float* __restrict__ fc2_b,
                     unsigned short* __restrict__ wbf, float* __restrict__ wsf) {
  const int blk = blockIdx.x;
  const int t = threadIdx.x;
  __shared__ float cw[128], ow2[128], red[128];
  if (blk < 40) {
    int o = blk * 256 + t;  // (n, kg) group of 8 k's
    const float* src;
    int dst;
    if (o < 2048) {  // W1: 2gi x 128n x 8kg
      int gi = o >> 10, rem = o & 1023, n = rem >> 3, kg = rem & 7;
      int g = gi ? 3 : 1;
      src = fc1_w + ((g << 7) + n) * 64 + kg * 8;
      int lane = (kg & 3) * 16 + (n & 15);
      int f = (n >> 4) * 2 + (kg >> 2);
      dst = ((gi * 16 + f) * 64 + lane) * 8;
    } else if (o < 6144) {  // Wk: 2gi x 128n x 16kg
      int o2 = o - 2048;
      int gi = o2 >> 11, rem = o2 & 2047, n = rem >> 4, kg = rem & 15;
      int g = gi ? 3 : 1;
      src = qkv_w + ((g * 384 + 128 + n) << 7) + kg * 8;
      int lane = (kg & 3) * 16 + (n & 15);
      int f = (n >> 4) * 4 + (kg >> 2);
      dst = 16384 + ((gi * 32 + f) * 64 + lane) * 8;
    } else {  // Wq
      int o2 = o - 6144;
      int gi = o2 >> 11, rem = o2 & 2047, n = rem >> 4, kg = rem & 15;
      int g = gi ? 3 : 1;
      src = qkv_w + ((g * 384 + n) << 7) + kg * 8;
      int lane = (kg & 3) * 16 + (n & 15);
      int f = (n >> 4) * 4 + (kg >> 2);
      dst = 49152 + ((gi * 32 + f) * 64 + lane) * 8;
    }
    float4 v0 = *(const float4*)src;
    float4 v1 = *(const float4*)(src + 4);
    uint4 p;
    p.x = pk2(v0.x, v0.y); p.y = pk2(v0.z, v0.w);
    p.z = pk2(v1.x, v1.y); p.w = pk2(v1.z, v1.w);
    *(uint4*)&wbf[dst] = p;
  } else {
    const int gi = blk - 40;
    const int g = gi ? 3 : 1;
    if (t < 128) {
      const float* fw = fc2_w + g * 32 * 128;
      float s = 0.f;
      for (int e = 0; e < 32; ++e) s += fw[e * 128 + t];
      cw[t] = s;
    }
    __syncthreads();
    if (t < 128) {
      const float* ow = out_w + g * 128 * 128;
      float s = 0.f;
      for (int h = 0; h < 128; ++h) s += ow[h * 128 + t] * cw[h];
      ow2[t] = s;
    }
    __syncthreads();
    float* wsg = wsf + gi * 1024;
    const float* qwv = qkv_w + (size_t)(g * 3 + 2) * 128 * 128;
    for (int o = t; o < 512; o += 256) {
      int hh = o >> 7, h2 = o & 127;
      float s = 0.f;
      for (int d = 0; d < 32; ++d) s += qwv[(hh * 32 + d) * 128 + h2] * ow2[hh * 32 + d];
      wsg[o] = s;
    }
    if (t < 4) {
      const float* qbv = qkv_b + g * 384 + 256;
      float s = 0.f;
      for (int d = 0; d < 32; ++d) s += qbv[t * 32 + d] * ow2[t * 32 + d];
      wsg[512 + t] = s;
    }
    if (t < 128) {
      float x = out_b[g * 128 + t] * cw[t];
      if (t < 32) x += fc2_b[g * 32 + t];
      red[t] = x;
    }
    __syncthreads();
    if (t < 64) {
      float s = red[t] + red[t + 64];
      for (int o = 32; o; o >>= 1) s += __shfl_xor(s, o, 64);
      if (t == 0) wsg[516] = s;
    }
  }
}

__global__ __launch_bounds__(512, 4)
void mixer(const float* __restrict__ agent_qs,
           const float* __restrict__ entities,
           const int* __restrict__ emask,
           const float* __restrict__ fc1_b,
           const float* __restrict__ qkv_b,
           const unsigned short* __restrict__ wbf,
           const float* __restrict__ wsf,
           float* __restrict__ out) {
  __shared__ __align__(16) unsigned short sEK[16384];  // E tiles (b*2048) then K rm (b*4096)
  __shared__ __align__(16) unsigned short sX1[16384];  // x1 tiles per b: [mt2][kc4][512]
  __shared__ __align__(16) unsigned short sQ[4096];    // per b: 8x128 rm
  __shared__ __align__(16) float sVW[1024];
  __shared__ float sVP[BPB][4][32];
  __shared__ int sMm[128];
  __shared__ float sS[8];

  const int t = threadIdx.x;
  const int lane = t & 63;
  const int w = t >> 6;
  const int r = lane & 15, kg = lane >> 4;
  const int bb0 = blockIdx.x * BPB;

  if (t < 128) sMm[t] = emask[bb0 * 32 + t];

  const short8* W1f = (const short8*)wbf;
  const short8* Wkf = (const short8*)(wbf + 16384);
  const short8* Wqf = (const short8*)(wbf + 49152);

  float wreg[4][2][4];

  for (int gi = 0; gi < 2; ++gi) {
    const int g = gi ? 3 : 1;
    // ---- phase A: stage E (bf16 tiles) + vw2 for this gi ----
    {
      const float4* Eg = (const float4*)entities + (size_t)bb0 * 512;
#pragma unroll
      for (int i = 0; i < 4; ++i) {
        int f4 = i * 512 + t;
        float4 v = Eg[f4];
        int k4 = f4 & 15, e = (f4 >> 4) & 31, bbi = f4 >> 9;
        int k = k4 * 4;
        int addr = bbi * 2048 + ((e >> 4) * 2 + (k >> 5)) * 512 + tile_addr(e & 15, k & 31);
        uint2 pkv;
        pkv.x = pk2(v.x, v.y);
        pkv.y = pk2(v.z, v.w);
        *(uint2*)&sEK[addr] = pkv;
      }
      if (t < 256) ((float4*)sVW)[t] = ((const float4*)(wsf + gi * 1024))[t];
    }
    __syncthreads();
    // ---- phase B: x1 = relu(E @ W1^T + b1), swapped operands: D[m=h][n=ent] ----
    {
      const int b = w >> 1, mtl = w & 1;
      f32x4 acc[8];
#pragma unroll
      for (int nt = 0; nt < 8; ++nt) acc[nt] = {0.f, 0.f, 0.f, 0.f};
#pragma unroll
      for (int kc = 0; kc < 2; ++kc) {
        short8 ef = *(const short8*)&sEK[b * 2048 + (mtl * 2 + kc) * 512 + tile_addr(r, kg * 8)];
#pragma unroll
        for (int nt = 0; nt < 8; ++nt)
          acc[nt] = __builtin_amdgcn_mfma_f32_16x16x32_bf16(
              W1f[(gi * 16 + nt * 2 + kc) * 64 + lane], ef, acc[nt], 0, 0, 0);
      }
      const float* b1 = fc1_b + g * 128;
#pragma unroll
      for (int nt = 0; nt < 8; ++nt) {
        int hbase = nt * 16 + kg * 4;
        float4 bb4 = *(const float4*)&b1[hbase];
        float v0 = fmaxf(acc[nt][0] + bb4.x, 0.f);
        float v1 = fmaxf(acc[nt][1] + bb4.y, 0.f);
        float v2 = fmaxf(acc[nt][2] + bb4.z, 0.f);
        float v3 = fmaxf(acc[nt][3] + bb4.w, 0.f);
        uint2 pkv;
        pkv.x = pk2(v0, v1);
        pkv.y = pk2(v2, v3);
        *(uint2*)&sX1[b * 4096 + (mtl * 4 + (hbase >> 5)) * 512 + tile_addr(r, hbase & 31)] = pkv;
      }
    }
    __syncthreads();
    // ---- phase C: K + Q + vproj (all read sX1; disjoint writes) ----
    {
      // K: D[m=h][n=ent], store rm-swizzled over E region
      const int b = w >> 1, mtl = w & 1;
      f32x4 acc[8];
#pragma unroll
      for (int nt = 0; nt < 8; ++nt) acc[nt] = {0.f, 0.f, 0.f, 0.f};
#pragma unroll
      for (int kc = 0; kc < 4; ++kc) {
        short8 xf = *(const short8*)&sX1[b * 4096 + (mtl * 4 + kc) * 512 + tile_addr(r, kg * 8)];
#pragma unroll
        for (int nt = 0; nt < 8; ++nt)
          acc[nt] = __builtin_amdgcn_mfma_f32_16x16x32_bf16(
              Wkf[(gi * 32 + nt * 4 + kc) * 64 + lane], xf, acc[nt], 0, 0, 0);
      }
      const float* bk = qkv_b + g * 384 + 128;
      const int ent = mtl * 16 + r;
#pragma unroll
      for (int nt = 0; nt < 8; ++nt) {
        int hbase = nt * 16 + kg * 4;
        float4 bb4 = *(const float4*)&bk[hbase];
        uint2 pkv;
        pkv.x = pk2(acc[nt][0] + bb4.x, acc[nt][1] + bb4.y);
        pkv.y = pk2(acc[nt][2] + bb4.z, acc[nt][3] + bb4.w);
        *(uint2*)&sEK[b * 4096 + rm_addr(ent, hbase)] = pkv;
      }
      // Q: packed 2 b's per tile; wave (mt = w>>2, ntp = w&3)
      const int mt = w >> 2, ntp = w & 3;
      const int b_rd = mt * 2 + (r >> 3);
      f32x4 qacc[2];
      qacc[0] = {0.f, 0.f, 0.f, 0.f};
      qacc[1] = {0.f, 0.f, 0.f, 0.f};
#pragma unroll
      for (int kc = 0; kc < 4; ++kc) {
        short8 xf = *(const short8*)&sX1[b_rd * 4096 + kc * 512 + tile_addr(r & 7, kg * 8)];
#pragma unroll
        for (int j = 0; j < 2; ++j)
          qacc[j] = __builtin_amdgcn_mfma_f32_16x16x32_bf16(
              Wqf[(gi * 32 + (ntp * 2 + j) * 4 + kc) * 64 + lane], xf, qacc[j], 0, 0, 0);
      }
      const float* bq = qkv_b + g * 384;
#pragma unroll
      for (int j = 0; j < 2; ++j) {
        int hbase = (ntp * 2 + j) * 16 + kg * 4;
        float4 bb4 = *(const float4*)&bq[hbase];
        uint2 pkv;
        pkv.x = pk2(qacc[j][0] + bb4.x, qacc[j][1] + bb4.y);
        pkv.y = pk2(qacc[j][2] + bb4.z, qacc[j][3] + bb4.w);
        *(uint2*)&sQ[(mt * 2 + (r >> 3)) * 1024 + rm_addr(r & 7, hbase)] = pkv;
      }
      // vproj: wave w -> (b=w>>1, hh = (w&1)*2 + lane>>5), lane e = lane&31
      const int vb = w >> 1;
      const int e = lane & 31;
      const int hh = (w & 1) * 2 + (lane >> 5);
      const int emt = e >> 4, er = e & 15;
      float a0 = sVW[512 + hh];
#pragma unroll
      for (int kc = 0; kc < 4; ++kc) {
#pragma unroll
        for (int gg = 0; gg < 4; ++gg) {
          uint4 u = *(const uint4*)&sX1[vb * 4096 + (emt * 4 + kc) * 512 + tile_addr(er, gg * 8)];
          const float* wv = &sVW[hh * 128 + kc * 32 + gg * 8];
          a0 = fmaf(bf2f(u.x & 0xffffu), wv[0], a0);
          a0 = fmaf(bf2f(u.x >> 16), wv[1], a0);
          a0 = fmaf(bf2f(u.y & 0xffffu), wv[2], a0);
          a0 = fmaf(bf2f(u.y >> 16), wv[3], a0);
          a0 = fmaf(bf2f(u.z & 0xffffu), wv[4], a0);
          a0 = fmaf(bf2f(u.z >> 16), wv[5], a0);
          a0 = fmaf(bf2f(u.w & 0xffffu), wv[6], a0);
          a0 = fmaf(bf2f(u.w >> 16), wv[7], a0);
        }
      }
      sVP[vb][hh][e] = a0;
    }
    __syncthreads();
    // ---- phase D: logits + softmax + final dot (waves 0-3, b=w) ----
    if (w < 4) {
      const int b = w;
      const int cl = r;
      bool ea0 = (sMm[b * 32 + cl] == 0);
      bool ea1 = (sMm[b * 32 + 16 + cl] == 0);
      bool aa[4];
#pragma unroll
      for (int reg = 0; reg < 4; ++reg) aa[reg] = (sMm[b * 32 + ((kg * 4 + reg) & 7)] == 0);
#pragma unroll
      for (int hh = 0; hh < 4; ++hh) {
        short8 af = *(const short8*)&sQ[b * 1024 + rm_addr(lane & 7, hh * 32 + kg * 8)];
        f32x4 z = {0.f, 0.f, 0.f, 0.f};
        short8 bf0 = *(const short8*)&sEK[b * 4096 + rm_addr(cl, hh * 32 + kg * 8)];
        f32x4 d0 = __builtin_amdgcn_mfma_f32_16x16x32_bf16(af, bf0, z, 0, 0, 0);
        short8 bf1 = *(const short8*)&sEK[b * 4096 + rm_addr(16 + cl, hh * 32 + kg * 8)];
        f32x4 d1 = __builtin_amdgcn_mfma_f32_16x16x32_bf16(af, bf1, z, 0, 0, 0);
#pragma unroll
        for (int reg = 0; reg < 4; ++reg) {
          float lg0 = (ea0 && aa[reg]) ? d0[reg] * SCALE : -1e30f;
          float lg1 = (ea1 && aa[reg]) ? d1[reg] * SCALE : -1e30f;
          float m = fmaxf(lg0, lg1);
          for (int o = 8; o; o >>= 1) m = fmaxf(m, __shfl_xor(m, o, 16));
          float p0 = lg0 > -1e29f ? __expf(lg0 - m) : 0.f;
          float p1 = lg1 > -1e29f ? __expf(lg1 - m) : 0.f;
          float s = p0 + p1;
          for (int o = 8; o; o >>= 1) s += __shfl_xor(s, o, 16);
          float inv = s > 0.f ? 1.f / s : 0.f;
          wreg[hh][0][reg] = p0 * inv;
          wreg[hh][1][reg] = p1 * inv;
        }
      }
      float c = 0.f;
#pragma unroll
      for (int hh = 0; hh < 4; ++hh) {
        float vp0 = sVP[b][hh][cl];
        float vp1 = sVP[b][hh][16 + cl];
        float s0 = wreg[hh][0][0] + wreg[hh][0][1] + wreg[hh][0][2] + wreg[hh][0][3];
        float s1 = wreg[hh][1][0] + wreg[hh][1][1] + wreg[hh][1][2] + wreg[hh][1][3];
        c = fmaf(vp0, s0, fmaf(vp1, s1, c));
      }
      for (int o = 16; o; o >>= 1) c += __shfl_xor(c, o, 32);
      if (lane == 0) {
        int cnt = 0;
        for (int a = 0; a < 8; ++a) cnt += (sMm[b * 32 + a] == 0);
        sS[gi * 4 + b] = c + sVW[516] * (float)cnt;
      }
    }
    __syncthreads();
  }

  if (t < BPB) {
    const float4* qs = (const float4*)(agent_qs + (size_t)(bb0 + t) * 8);
    float4 a = qs[0], b4 = qs[1];
    float q = a.x + a.y + a.z + a.w + b4.x + b4.y + b4.z + b4.w;
    out[bb0 + t] = q + sS[t] * 0.125f + sS[4 + t] * (1.f / 256.f);
  }
}

extern "C" void kernel_launch(void* const* d_in, const int* in_sizes, int n_in,
                              void* d_out, int out_size, void* d_ws, size_t ws_size,
                              hipStream_t stream) {
  const float* agent_qs = (const float*)d_in[0];
  const float* entities = (const float*)d_in[1];
  const int* emask = (const int*)d_in[2];
  const float* fc1_w = (const float*)d_in[3];
  const float* fc1_b = (const float*)d_in[4];
  const float* qkv_w = (const float*)d_in[5];
  const float* qkv_b = (const float*)d_in[6];
  const float* out_w = (const float*)d_in[7];
  const float* out_b = (const float*)d_in[8];
  const float* fc2_w = (const float*)d_in[9];
  const float* fc2_b = (const float*)d_in[10];
  float* out = (float*)d_out;
  unsigned short* wbf = (unsigned short*)d_ws;
  float* wsf = (float*)((char*)d_ws + 163840);

  prep<<<42, 256, 0, stream>>>(fc1_w, qkv_w, qkv_b, out_w, out_b, fc2_w, fc2_b, wbf, wsf);
  mixer<<<NBLK, 512, 0, stream>>>(agent_qs, entities, emask, fc1_b, qkv_b, wbf, wsf, out);
}

// Round 5
// 151.931 us; speedup vs baseline: 1.1489x; 1.1489x over previous
//
#include <hip/hip_runtime.h>
#include <math.h>

#define BPB 2
#define NBLK 2048
#define SCALE 0.17677669529663687f

typedef short short8 __attribute__((ext_vector_type(8)));
typedef float f32x4 __attribute__((ext_vector_type(4)));
typedef unsigned short ushort_t;

__device__ __forceinline__ unsigned short f2bf(float x) {
  unsigned int u = __float_as_uint(x);
  u += 0x7fffu + ((u >> 16) & 1u);
  return (unsigned short)(u >> 16);
}
__device__ __forceinline__ unsigned pk2(float a, float b) {
  return (unsigned)f2bf(a) | ((unsigned)f2bf(b) << 16);
}
// [16 rows][32 k] bf16 tile (1KB), XOR-swizzled 16B granules
__device__ __forceinline__ int tile_addr(int r, int k) {
  int g = k >> 3;
  int p = (g ^ ((r >> 1) & 3)) & 3;
  return r * 32 + p * 8 + (k & 7);
}
// row-major [rows][128] bf16, rotate-XOR swizzle
__device__ __forceinline__ int rm_addr(int r, int k) {
  int g = k >> 3;
  int r3 = r & 7;
  int rot = ((r3 << 2) | (r3 >> 1)) & 7;
  int p = (g & 8) | ((g & 7) ^ rot);
  return r * 128 + p * 8 + (k & 7);
}

// wbf (shorts): W1 [0,16384): ((gi*16 + nt*2+kc)*64+lane)*8
//   Wkv [16384,53248): ((gi*36 + nt*4+kc)*64+lane)*8   (nt=8 tile = vw2 rows 0..3, rows 4..15 zero)
//   Wq  [53248,86016): ((gi*32 + nt*4+kc)*64+lane)*8
// wsf (floats at byte 172032): per gi stride 1024: [512..515] vb2, [516] const
__global__ void prep(const float* __restrict__ fc1_w, const float* __restrict__ qkv_w,
                     const float* __restrict__ qkv_b, const float* __restrict__ out_w,
                     const float* __restrict__ out_b, const float* __restrict__ fc2_w,
                     const float* __restrict__ fc2_b,
                     unsigned short* __restrict__ wbf, float* __restrict__ wsf) {
  const int blk = blockIdx.x;
  const int t = threadIdx.x;
  __shared__ float cw[128], red[256], ow2s[32];
  if (blk < 40) {
    int o = blk * 256 + t;
    const float* src;
    int dst;
    if (o < 2048) {  // W1: 2gi x 128n x 8kg
      int gi = o >> 10, rem = o & 1023, n = rem >> 3, kg = rem & 7;
      int g = gi ? 3 : 1;
      src = fc1_w + ((g << 7) + n) * 64 + kg * 8;
      int lane = (kg & 3) * 16 + (n & 15);
      int f = (n >> 4) * 2 + (kg >> 2);
      dst = ((gi * 16 + f) * 64 + lane) * 8;
    } else if (o < 6144) {  // Wk -> Wkv nt<8
      int o2 = o - 2048;
      int gi = o2 >> 11, rem = o2 & 2047, n = rem >> 4, kg = rem & 15;
      int g = gi ? 3 : 1;
      src = qkv_w + ((g * 384 + 128 + n) << 7) + kg * 8;
      int lane = (kg & 3) * 16 + (n & 15);
      int f = (n >> 4) * 4 + (kg >> 2);
      dst = 16384 + ((gi * 36 + f) * 64 + lane) * 8;
    } else {  // Wq
      int o2 = o - 6144;
      int gi = o2 >> 11, rem = o2 & 2047, n = rem >> 4, kg = rem & 15;
      int g = gi ? 3 : 1;
      src = qkv_w + ((g * 384 + n) << 7) + kg * 8;
      int lane = (kg & 3) * 16 + (n & 15);
      int f = (n >> 4) * 4 + (kg >> 2);
      dst = 53248 + ((gi * 32 + f) * 64 + lane) * 8;
    }
    float4 v0 = *(const float4*)src;
    float4 v1 = *(const float4*)(src + 4);
    uint4 p;
    p.x = pk2(v0.x, v0.y); p.y = pk2(v0.z, v0.w);
    p.z = pk2(v1.x, v1.y); p.w = pk2(v1.z, v1.w);
    *(uint4*)&wbf[dst] = p;
  } else {
    const int mb = blk - 40;       // 8 blocks: gi x hh
    const int gi = mb >> 2, hh = mb & 3;
    const int g = gi ? 3 : 1;
    // cw[h2] = sum_e fc2_w[g][e][h2]
    {
      const float* fw = fc2_w + g * 4096;
      int h2 = t & 127, half = t >> 7;
      float s = 0.f;
      for (int e = half * 16; e < half * 16 + 16; ++e) s += fw[e * 128 + h2];
      red[t] = s;
    }
    __syncthreads();
    if (t < 128) cw[t] = red[t] + red[t + 128];
    __syncthreads();
    // ow2 slice [hh*32, hh*32+32)
    {
      const float* ow = out_w + g * 16384;
      int hp = hh * 32 + (t & 31), ch = t >> 5;
      float s = 0.f;
      for (int h = ch * 16; h < ch * 16 + 16; ++h) s += ow[h * 128 + hp] * cw[h];
      red[t] = s;
    }
    __syncthreads();
    if (t < 32) {
      float s = 0.f;
      for (int c = 0; c < 8; ++c) s += red[c * 32 + t];
      ow2s[t] = s;
    }
    __syncthreads();
    // vw2[hh][h2] -> bf16 fragment tile nt=8
    {
      const float* qwv = qkv_w + (size_t)(g * 3 + 2) * 16384;
      int h2 = t & 127, half = t >> 7;
      float s = 0.f;
      for (int d = half * 16; d < half * 16 + 16; ++d)
        s += qwv[(hh * 32 + d) * 128 + h2] * ow2s[d];
      red[t] = s;
    }
    __syncthreads();
    if (t < 128) {
      float v = red[t] + red[t + 128];
      int k = t, kc = k >> 5, kg2 = k >> 3, j = k & 7;
      wbf[16384 + ((gi * 36 + 32 + kc) * 64 + ((kg2 & 3) * 16 + hh)) * 8 + j] = f2bf(v);
    }
    // vb2[hh]
    if (t < 32) red[t] = qkv_b[g * 384 + 256 + hh * 32 + t] * ow2s[t];
    __syncthreads();
    if (t < 32) {
      float s = red[t];
      for (int o = 16; o; o >>= 1) s += __shfl_xor(s, o, 32);
      if (t == 0) wsf[gi * 1024 + 512 + hh] = s;
    }
    if (hh == 0) {
      // zero rows 4..15 of the vw2 tile
      for (int idx = t; idx < 1536; idx += 256) {
        int n = 4 + (idx >> 7), k = idx & 127;
        int kc = k >> 5, kg2 = k >> 3, j = k & 7;
        wbf[16384 + ((gi * 36 + 32 + kc) * 64 + ((kg2 & 3) * 16 + n)) * 8 + j] = 0;
      }
      // const = sum_h out_b*cw + sum_e fc2_b
      if (t < 128) red[t] = out_b[g * 128 + t] * cw[t] + (t < 32 ? fc2_b[g * 32 + t] : 0.f);
      __syncthreads();
      if (t < 64) {
        float s = red[t] + red[t + 64];
        for (int o = 32; o; o >>= 1) s += __shfl_xor(s, o, 64);
        if (t == 0) wsf[gi * 1024 + 516] = s;
      }
    }
  }
}

__global__ __launch_bounds__(256, 3)
void mixer(const float* __restrict__ agent_qs,
           const float* __restrict__ entities,
           const int* __restrict__ emask,
           const float* __restrict__ fc1_b,
           const float* __restrict__ qkv_b,
           const unsigned short* __restrict__ wbf,
           const float* __restrict__ wsf,
           float* __restrict__ out) {
  __shared__ __align__(16) ushort_t sE[4096];   // E tiles: per b 2048 [mt2][kc2][512]
  __shared__ __align__(16) ushort_t sX1[8192];  // x1 tiles: per b 4096 [mt2][kc4][512]
  __shared__ __align__(16) ushort_t sK[8192];   // K rm: per b 4096 [32 ent][128]
  __shared__ __align__(16) ushort_t sQ[2048];   // per b 1024: [8 agent][128]
  __shared__ float sVP[BPB][4][32];
  __shared__ int sMm[64];
  __shared__ float sS[4];

  const int t = threadIdx.x;
  const int lane = t & 63;
  const int w = t >> 6;
  const int r = lane & 15, kg = lane >> 4;
  const int bb0 = blockIdx.x * BPB;

  if (t < 64) sMm[t] = emask[bb0 * 32 + t];

  const short8* W1f = (const short8*)wbf;
  const short8* Wkvf = (const short8*)(wbf + 16384);
  const short8* Wqf = (const short8*)(wbf + 53248);

  // ---- stage E once (same data for both groups) ----
  {
    const float4* Eg = (const float4*)entities + (size_t)bb0 * 512;
#pragma unroll
    for (int i = 0; i < 4; ++i) {
      int f4 = i * 256 + t;
      float4 v = Eg[f4];
      int k4 = f4 & 15, e = (f4 >> 4) & 31, bbi = f4 >> 9;
      int k = k4 * 4;
      int addr = bbi * 2048 + ((e >> 4) * 2 + (k >> 5)) * 512 + tile_addr(e & 15, k & 31);
      uint2 pkv;
      pkv.x = pk2(v.x, v.y);
      pkv.y = pk2(v.z, v.w);
      *(uint2*)&sE[addr] = pkv;
    }
  }
  __syncthreads();

  float wreg[4][2][4];

  for (int gi = 0; gi < 2; ++gi) {
    const int g = gi ? 3 : 1;
    // ---- phase B: x1 = relu(E @ W1^T + b1); wave -> (b, mtl) ----
    {
      const int b = w >> 1, mtl = w & 1;
      f32x4 acc[8];
#pragma unroll
      for (int nt = 0; nt < 8; ++nt) acc[nt] = {0.f, 0.f, 0.f, 0.f};
#pragma unroll
      for (int kc = 0; kc < 2; ++kc) {
        short8 ef = *(const short8*)&sE[b * 2048 + (mtl * 2 + kc) * 512 + tile_addr(r, kg * 8)];
#pragma unroll
        for (int nt = 0; nt < 8; ++nt)
          acc[nt] = __builtin_amdgcn_mfma_f32_16x16x32_bf16(
              W1f[(gi * 16 + nt * 2 + kc) * 64 + lane], ef, acc[nt], 0, 0, 0);
      }
      const float* b1 = fc1_b + g * 128;
#pragma unroll
      for (int nt = 0; nt < 8; ++nt) {
        int hbase = nt * 16 + kg * 4;
        float4 bb4 = *(const float4*)&b1[hbase];
        float v0 = fmaxf(acc[nt][0] + bb4.x, 0.f);
        float v1 = fmaxf(acc[nt][1] + bb4.y, 0.f);
        float v2 = fmaxf(acc[nt][2] + bb4.z, 0.f);
        float v3 = fmaxf(acc[nt][3] + bb4.w, 0.f);
        uint2 pkv;
        pkv.x = pk2(v0, v1);
        pkv.y = pk2(v2, v3);
        *(uint2*)&sX1[b * 4096 + (mtl * 4 + (hbase >> 5)) * 512 + tile_addr(r, hbase & 31)] = pkv;
      }
    }
    __syncthreads();
    // ---- phase C: [K | vproj] GEMM + Q GEMM ----
    {
      const int b = w >> 1, mtl = w & 1;
      f32x4 acc[9];
#pragma unroll
      for (int nt = 0; nt < 9; ++nt) acc[nt] = {0.f, 0.f, 0.f, 0.f};
#pragma unroll
      for (int kc = 0; kc < 4; ++kc) {
        short8 xf = *(const short8*)&sX1[b * 4096 + (mtl * 4 + kc) * 512 + tile_addr(r, kg * 8)];
#pragma unroll
        for (int nt = 0; nt < 9; ++nt)
          acc[nt] = __builtin_amdgcn_mfma_f32_16x16x32_bf16(
              Wkvf[(gi * 36 + nt * 4 + kc) * 64 + lane], xf, acc[nt], 0, 0, 0);
      }
      const float* bk = qkv_b + g * 384 + 128;
      const int ent = mtl * 16 + r;
#pragma unroll
      for (int nt = 0; nt < 8; ++nt) {
        int hbase = nt * 16 + kg * 4;
        float4 bb4 = *(const float4*)&bk[hbase];
        uint2 pkv;
        pkv.x = pk2(acc[nt][0] + bb4.x, acc[nt][1] + bb4.y);
        pkv.y = pk2(acc[nt][2] + bb4.z, acc[nt][3] + bb4.w);
        *(uint2*)&sK[b * 4096 + rm_addr(ent, hbase)] = pkv;
      }
      if (kg == 0) {
#pragma unroll
        for (int reg = 0; reg < 4; ++reg)
          sVP[b][reg][ent] = acc[8][reg] + wsf[gi * 1024 + 512 + reg];
      }
      // Q: wave handles nt tiles {2w, 2w+1}; rows pack both b's agents
      f32x4 qacc[2];
      qacc[0] = {0.f, 0.f, 0.f, 0.f};
      qacc[1] = {0.f, 0.f, 0.f, 0.f};
      const int b_rd = r >> 3;
#pragma unroll
      for (int kc = 0; kc < 4; ++kc) {
        short8 xf = *(const short8*)&sX1[b_rd * 4096 + kc * 512 + tile_addr(r & 7, kg * 8)];
#pragma unroll
        for (int j = 0; j < 2; ++j)
          qacc[j] = __builtin_amdgcn_mfma_f32_16x16x32_bf16(
              Wqf[(gi * 32 + (w * 2 + j) * 4 + kc) * 64 + lane], xf, qacc[j], 0, 0, 0);
      }
      const float* bq = qkv_b + g * 384;
#pragma unroll
      for (int j = 0; j < 2; ++j) {
        int hbase = (w * 2 + j) * 16 + kg * 4;
        float4 bb4 = *(const float4*)&bq[hbase];
        uint2 pkv;
        pkv.x = pk2(qacc[j][0] + bb4.x, qacc[j][1] + bb4.y);
        pkv.y = pk2(qacc[j][2] + bb4.z, qacc[j][3] + bb4.w);
        *(uint2*)&sQ[(r >> 3) * 1024 + rm_addr(r & 7, hbase)] = pkv;
      }
    }
    __syncthreads();
    // ---- phase D: attention + reduction; waves 0-1 (b = w) ----
    if (w < BPB) {
      const int b = w;
      const int cl = r;
      bool ea0 = (sMm[b * 32 + cl] == 0);
      bool ea1 = (sMm[b * 32 + 16 + cl] == 0);
      bool aa[4];
#pragma unroll
      for (int reg = 0; reg < 4; ++reg) aa[reg] = (sMm[b * 32 + ((kg * 4 + reg) & 7)] == 0);
#pragma unroll
      for (int hh = 0; hh < 4; ++hh) {
        short8 af = *(const short8*)&sQ[b * 1024 + rm_addr(lane & 7, hh * 32 + kg * 8)];
        f32x4 z = {0.f, 0.f, 0.f, 0.f};
        short8 bf0 = *(const short8*)&sK[b * 4096 + rm_addr(cl, hh * 32 + kg * 8)];
        f32x4 d0 = __builtin_amdgcn_mfma_f32_16x16x32_bf16(af, bf0, z, 0, 0, 0);
        short8 bf1 = *(const short8*)&sK[b * 4096 + rm_addr(16 + cl, hh * 32 + kg * 8)];
        f32x4 d1 = __builtin_amdgcn_mfma_f32_16x16x32_bf16(af, bf1, z, 0, 0, 0);
#pragma unroll
        for (int reg = 0; reg < 4; ++reg) {
          float lg0 = (ea0 && aa[reg]) ? d0[reg] * SCALE : -1e30f;
          float lg1 = (ea1 && aa[reg]) ? d1[reg] * SCALE : -1e30f;
          float m = fmaxf(lg0, lg1);
          for (int o = 8; o; o >>= 1) m = fmaxf(m, __shfl_xor(m, o, 16));
          float p0 = lg0 > -1e29f ? __expf(lg0 - m) : 0.f;
          float p1 = lg1 > -1e29f ? __expf(lg1 - m) : 0.f;
          float s = p0 + p1;
          for (int o = 8; o; o >>= 1) s += __shfl_xor(s, o, 16);
          float inv = s > 0.f ? 1.f / s : 0.f;
          wreg[hh][0][reg] = p0 * inv;
          wreg[hh][1][reg] = p1 * inv;
        }
      }
      float c = 0.f;
#pragma unroll
      for (int hh = 0; hh < 4; ++hh) {
        float vp0 = sVP[b][hh][cl];
        float vp1 = sVP[b][hh][16 + cl];
        float s0 = wreg[hh][0][0] + wreg[hh][0][1] + wreg[hh][0][2] + wreg[hh][0][3];
        float s1 = wreg[hh][1][0] + wreg[hh][1][1] + wreg[hh][1][2] + wreg[hh][1][3];
        c = fmaf(vp0, s0, fmaf(vp1, s1, c));
      }
      for (int o = 16; o; o >>= 1) c += __shfl_xor(c, o, 32);
      if (lane == 0) {
        int cnt = 0;
        for (int a = 0; a < 8; ++a) cnt += (sMm[b * 32 + a] == 0);
        sS[gi * 2 + b] = c + wsf[gi * 1024 + 516] * (float)cnt;
      }
    }
    __syncthreads();
  }

  if (t < BPB) {
    const float4* qs = (const float4*)(agent_qs + (size_t)(bb0 + t) * 8);
    float4 a = qs[0], b4 = qs[1];
    float q = a.x + a.y + a.z + a.w + b4.x + b4.y + b4.z + b4.w;
    out[bb0 + t] = q + sS[t] * 0.125f + sS[2 + t] * (1.f / 256.f);
  }
}

extern "C" void kernel_launch(void* const* d_in, const int* in_sizes, int n_in,
                              void* d_out, int out_size, void* d_ws, size_t ws_size,
                              hipStream_t stream) {
  const float* agent_qs = (const float*)d_in[0];
  const float* entities = (const float*)d_in[1];
  const int* emask = (const int*)d_in[2];
  const float* fc1_w = (const float*)d_in[3];
  const float* fc1_b = (const float*)d_in[4];
  const float* qkv_w = (const float*)d_in[5];
  const float* qkv_b = (const float*)d_in[6];
  const float* out_w = (const float*)d_in[7];
  const float* out_b = (const float*)d_in[8];
  const float* fc2_w = (const float*)d_in[9];
  const float* fc2_b = (const float*)d_in[10];
  float* out = (float*)d_out;
  unsigned short* wbf = (unsigned short*)d_ws;
  float* wsf = (float*)((char*)d_ws + 172032);

  prep<<<48, 256, 0, stream>>>(fc1_w, qkv_w, qkv_b, out_w, out_b, fc2_w, fc2_b, wbf, wsf);
  mixer<<<NBLK, 256, 0, stream>>>(agent_qs, entities, emask, fc1_b, qkv_b, wbf, wsf, out);
}